// Round 5
// baseline (881.316 us; speedup 1.0000x reference)
//
#include <hip/hip_runtime.h>
#include <math.h>

#define NROWS 524288
constexpr float EPSW = 1e-8f;

// ---------------- workspace layout (float offsets) ----------------
constexpr int OFF_WVT     = 0;       // 64x64   WvT[d][j]
constexpr int OFF_WIHT_BG = 4096;    // 64x192
constexpr int OFF_WHHT_BG = 16384;
constexpr int OFF_WIHT_FG = 28672;
constexpr int OFF_WHHT_FG = 40960;
constexpr int OFF_W1T_BG  = 53248;   // 64x128
constexpr int OFF_W2T_BG  = 61440;   // 128x64
constexpr int OFF_W1T_FG  = 69632;
constexpr int OFF_W2T_FG  = 77824;
constexpr int OFF_WQT_BG  = 86016;   // 64x64
constexpr int OFF_WQT_FG  = 90112;
constexpr int OFF_SLOTS   = 94208;   // 3x64
constexpr int OFF_QG      = 94400;   // 2 sets x 3 x 64
constexpr int OFF_QS      = 94784;   // 2 sets x 6
constexpr int OFF_M       = 94800;   // 2 sets x 192
constexpr int OFF_W       = 95184;   // 2 sets x 3 (then CM 2x3)
constexpr int OFF_CM      = 95190;
constexpr int OFF_DONE    = 95200;   // 2 ints

__device__ __forceinline__ float wave_sum(float v) {
#pragma unroll
  for (int m = 1; m < 64; m <<= 1) v += __shfl_xor(v, m, 64);
  return v;
}

// ---------------- q -> qk -> (qg, QG, QB) for one slot (one wave) ----------------
__device__ void emit_q(int lane, float snew,
                       const float* __restrict__ lnq_g, const float* __restrict__ lnq_b,
                       const float* WqT, int qstride, const float* __restrict__ Wk,
                       const float* __restrict__ g_in, const float* __restrict__ b_in,
                       float* scratch,
                       float* __restrict__ qg_out, float* __restrict__ qs_out, int s)
{
  float mean = wave_sum(snew) * (1.0f / 64.0f);
  float d = snew - mean;
  float var = wave_sum(d * d) * (1.0f / 64.0f);
  float lns = d * rsqrtf(var + 1e-5f) * lnq_g[lane] + lnq_b[lane];
  scratch[lane] = lns;
  float q = 0.f;
#pragma unroll 8
  for (int dd = 0; dd < 64; ++dd) q = fmaf(scratch[dd], WqT[dd * qstride + lane], q);
  q *= 0.125f;
  scratch[lane] = q;
  float qk = 0.f;
#pragma unroll 8
  for (int j = 0; j < 64; ++j) qk = fmaf(scratch[j], Wk[j * 64 + lane], qk);
  float qgv = qk * g_in[lane];
  qg_out[lane] = qgv;
  float QG = wave_sum(qgv);
  float QB = wave_sum(qk * b_in[lane]);
  if (lane == 0) { qs_out[s] = QG; qs_out[3 + s] = QB; }
}

// ---------------- prep: transposes + zero + init (13 blocks) ----------------
struct TJob { const float* src; int RC; int Cshift; int dstOff; };
struct TArgs { TJob j[11]; };

__global__ void prep_k(TArgs a,
                       const float* __restrict__ noise_fg, const float* __restrict__ noise_bg,
                       const float* __restrict__ g_in, const float* __restrict__ b_in,
                       const float* __restrict__ mu_fg, const float* __restrict__ logsig_fg,
                       const float* __restrict__ mu_bg, const float* __restrict__ logsig_bg,
                       const float* __restrict__ lnq_fg_g, const float* __restrict__ lnq_fg_b,
                       const float* __restrict__ lnq_bg_g, const float* __restrict__ lnq_bg_b,
                       const float* __restrict__ Wk,
                       const float* __restrict__ Wq_bg, const float* __restrict__ Wq_fg,
                       float* __restrict__ ws)
{
  __shared__ float wqT[2][64 * 65];
  __shared__ float scratch[64];
  const int b = blockIdx.x, tid = threadIdx.x;
  if (b < 11) {
    TJob jb = a.j[b];
    const int C = 1 << jb.Cshift;
    const int R = jb.RC >> jb.Cshift;
    float* dst = ws + jb.dstOff;
    for (int e = tid; e < jb.RC; e += blockDim.x) {
      int r = e >> jb.Cshift;
      int c = e & (C - 1);
      dst[c * R + r] = jb.src[e];
    }
  } else if (b == 11) {
    for (int i = tid; i < 384; i += 256) ws[OFF_M + i] = 0.f;
    if (tid < 12) ws[OFF_W + tid] = 0.f;
    if (tid < 2) ((int*)(ws + OFF_DONE))[tid] = 0;
  } else {
    // in-block padded transpose of Wq_bg/Wq_fg, then init slots + emit_q x3
    for (int e = tid; e < 4096; e += 256) {
      int r = e >> 6, c = e & 63;
      wqT[0][c * 65 + r] = Wq_bg[e];
      wqT[1][c * 65 + r] = Wq_fg[e];
    }
    __syncthreads();
    if (tid < 64) {
      const int lane = tid;
      float s0 = mu_bg[lane] + __expf(logsig_bg[lane]) * noise_bg[lane];
      float s1 = mu_fg[lane] + __expf(logsig_fg[lane]) * noise_fg[lane];
      float s2 = mu_fg[lane] + __expf(logsig_fg[lane]) * noise_fg[64 + lane];
      ws[OFF_SLOTS + lane] = s0;
      ws[OFF_SLOTS + 64 + lane] = s1;
      ws[OFF_SLOTS + 128 + lane] = s2;
      emit_q(lane, s0, lnq_bg_g, lnq_bg_b, wqT[0], 65, Wk, g_in, b_in, scratch,
             ws + OFF_QG + 0, ws + OFF_QS, 0);
      emit_q(lane, s1, lnq_fg_g, lnq_fg_b, wqT[1], 65, Wk, g_in, b_in, scratch,
             ws + OFF_QG + 64, ws + OFF_QS, 1);
      emit_q(lane, s2, lnq_fg_g, lnq_fg_b, wqT[1], 65, Wk, g_in, b_in, scratch,
             ws + OFF_QG + 128, ws + OFF_QS, 2);
    }
  }
}

// ---------------- pointers for the fused finalizer ----------------
struct FinPtrs {
  const float *g_in, *b_in, *gbg_bih, *gbg_bhh, *gfg_bih, *gfg_bhh,
      *mbg_ln_g, *mbg_ln_b, *mfg_ln_g, *mfg_ln_b, *mbg_b1, *mbg_b2, *mfg_b1, *mfg_b2,
      *lnq_fg_g, *lnq_fg_b, *lnq_bg_g, *lnq_bg_b, *Wk;
};

// slot update: upd -> GRU -> MLP -> (emit_q for next iter | write slots)
__device__ void finalize(int tid, float* __restrict__ ws, int set,
                         float* __restrict__ out_slots, const FinPtrs fp)
{
  __shared__ float sA[3][64], sU[3][64], sH[3][64], sHid[3][128];
  const int wid = tid >> 6, lane = tid & 63;
  const bool act = (wid < 3);
  const bool bg = (wid == 0);
  float* M_out = ws + OFF_M + set * 192;
  float* W_out = ws + OFF_W + set * 3;
  float* CM_out = ws + OFF_CM + set * 3;

  float Wsum = 1.f, h = 0.f;
  if (act) {
    Wsum = atomicAdd(&W_out[wid], 0.f);
    float CM = atomicAdd(&CM_out[wid], 0.f);
    float Mv = atomicAdd(&M_out[wid * 64 + lane], 0.f);
    sA[wid][lane] = fp.g_in[lane] * (Mv - CM) + fp.b_in[lane] * Wsum;
  }
  __syncthreads();
  if (act) {
    const float* WvT = ws + OFF_WVT;
    float upd = 0.f;
#pragma unroll 8
    for (int d = 0; d < 64; ++d) upd = fmaf(sA[wid][d], WvT[d * 64 + lane], upd);
    upd /= Wsum;
    h = ws[OFF_SLOTS + wid * 64 + lane];
    sU[wid][lane] = upd; sH[wid][lane] = h;
  }
  __syncthreads();
  float hp = 0.f, lnh = 0.f;
  if (act) {
    const float* wihT = ws + (bg ? OFF_WIHT_BG : OFF_WIHT_FG);
    const float* whhT = ws + (bg ? OFF_WHHT_BG : OFF_WHHT_FG);
    const float* bih = bg ? fp.gbg_bih : fp.gfg_bih;
    const float* bhh = bg ? fp.gbg_bhh : fp.gfg_bhh;
    float gi0 = bih[lane], gi1 = bih[64 + lane], gi2 = bih[128 + lane];
    float gh0 = bhh[lane], gh1 = bhh[64 + lane], gh2 = bhh[128 + lane];
#pragma unroll 8
    for (int d = 0; d < 64; ++d) {
      float u = sU[wid][d], hh = sH[wid][d];
      const float* wi = &wihT[d * 192];
      const float* wh = &whhT[d * 192];
      gi0 = fmaf(u, wi[lane], gi0);
      gi1 = fmaf(u, wi[64 + lane], gi1);
      gi2 = fmaf(u, wi[128 + lane], gi2);
      gh0 = fmaf(hh, wh[lane], gh0);
      gh1 = fmaf(hh, wh[64 + lane], gh1);
      gh2 = fmaf(hh, wh[128 + lane], gh2);
    }
    float r = 1.f / (1.f + __expf(-(gi0 + gh0)));
    float z = 1.f / (1.f + __expf(-(gi1 + gh1)));
    float nn = tanhf(fmaf(r, gh2, gi2));
    hp = (1.f - z) * nn + z * h;
    float mean = wave_sum(hp) * (1.f / 64.f);
    float dv = hp - mean;
    float var = wave_sum(dv * dv) * (1.f / 64.f);
    const float* mlg = bg ? fp.mbg_ln_g : fp.mfg_ln_g;
    const float* mlb = bg ? fp.mbg_ln_b : fp.mfg_ln_b;
    lnh = dv * rsqrtf(var + 1e-5f) * mlg[lane] + mlb[lane];
  }
  __syncthreads();
  if (act) sA[wid][lane] = lnh;
  __syncthreads();
  if (act) {
    const float* w1T = ws + (bg ? OFF_W1T_BG : OFF_W1T_FG);
    const float* b1 = bg ? fp.mbg_b1 : fp.mfg_b1;
    float h1a = b1[lane], h1b = b1[64 + lane];
#pragma unroll 8
    for (int d = 0; d < 64; ++d) {
      float t = sA[wid][d];
      h1a = fmaf(t, w1T[d * 128 + lane], h1a);
      h1b = fmaf(t, w1T[d * 128 + 64 + lane], h1b);
    }
    sHid[wid][lane] = fmaxf(h1a, 0.f);
    sHid[wid][64 + lane] = fmaxf(h1b, 0.f);
  }
  __syncthreads();
  if (act) {
    const float* w2T = ws + (bg ? OFF_W2T_BG : OFF_W2T_FG);
    const float* b2 = bg ? fp.mbg_b2 : fp.mfg_b2;
    float o = b2[lane];
#pragma unroll 8
    for (int j = 0; j < 128; ++j) o = fmaf(sHid[wid][j], w2T[j * 64 + lane], o);
    float snew = hp + o;
    ws[OFF_SLOTS + wid * 64 + lane] = snew;
    if (out_slots) {
      out_slots[wid * 64 + lane] = snew;
    } else {
      const float* lqg = bg ? fp.lnq_bg_g : fp.lnq_fg_g;
      const float* lqb = bg ? fp.lnq_bg_b : fp.lnq_fg_b;
      int so = set ^ 1;
      emit_q(lane, snew, lqg, lqb, ws + (bg ? OFF_WQT_BG : OFF_WQT_FG), 64,
             fp.Wk, fp.g_in, fp.b_in, sA[wid],
             ws + OFF_QG + so * 192 + wid * 64, ws + OFF_QS + so * 6, wid);
    }
  }
}

// ---------------- streaming attention pass: lean-register, TLP latency hiding ----------------
template <int WRITE_OUT>
__launch_bounds__(256, 8) __global__ void attn_pass_k(
    const float* __restrict__ x, float* __restrict__ ws, int set,
    float* __restrict__ attn_out, float* __restrict__ out_slots, FinPtrs fp)
{
  constexpr int NBLK = 2048;
  const float* qg = ws + OFF_QG + set * 192;
  const float* qs = ws + OFF_QS + set * 6;
  float* M_out = ws + OFF_M + set * 192;
  float* W_out = ws + OFF_W + set * 3;
  float* CM_out = ws + OFF_CM + set * 3;
  int* done = (int*)(ws + OFF_DONE) + set;

  const int tid = threadIdx.x, wid = tid >> 6, lane = tid & 63;
  const int sub = lane & 15, grp = lane >> 4;
  const float4* qgv = (const float4*)qg;
  const float4 qg0 = qgv[sub], qg1 = qgv[16 + sub], qg2 = qgv[32 + sub];
  const float QG0 = qs[0], QG1 = qs[1], QG2 = qs[2];
  const float QB0 = qs[3], QB1 = qs[4], QB2 = qs[5];

  // named accumulators (no arrays -> no scratch risk)
  float m0x = 0, m0y = 0, m0z = 0, m0w = 0;
  float m1x = 0, m1y = 0, m1z = 0, m1w = 0;
  float m2x = 0, m2y = 0, m2z = 0, m2w = 0;
  float aW0 = 0, aW1 = 0, aW2 = 0, aC0 = 0, aC1 = 0, aC2 = 0;

  auto proc = [&](const float4 v, int row) {
    float s  = (v.x + v.y) + (v.z + v.w);
    float q2 = fmaf(v.x, v.x, fmaf(v.y, v.y, fmaf(v.z, v.z, v.w * v.w)));
    float d0 = fmaf(v.x, qg0.x, fmaf(v.y, qg0.y, fmaf(v.z, qg0.z, v.w * qg0.w)));
    float d1 = fmaf(v.x, qg1.x, fmaf(v.y, qg1.y, fmaf(v.z, qg1.z, v.w * qg1.w)));
    float d2 = fmaf(v.x, qg2.x, fmaf(v.y, qg2.y, fmaf(v.z, qg2.z, v.w * qg2.w)));
#pragma unroll
    for (int m = 1; m < 16; m <<= 1) {
      s  += __shfl_xor(s, m, 64);
      q2 += __shfl_xor(q2, m, 64);
      d0 += __shfl_xor(d0, m, 64);
      d1 += __shfl_xor(d1, m, 64);
      d2 += __shfl_xor(d2, m, 64);
    }
    float mean = s * 0.015625f;
    float var  = fmaf(q2, 0.015625f, -mean * mean);
    float rs   = rsqrtf(var + 1e-5f);
    float l0 = fmaf(rs, fmaf(-mean, QG0, d0), QB0);
    float l1 = fmaf(rs, fmaf(-mean, QG1, d1), QB1);
    float l2 = fmaf(rs, fmaf(-mean, QG2, d2), QB2);
    float mx = fmaxf(l0, fmaxf(l1, l2));
    float e0 = __expf(l0 - mx), e1 = __expf(l1 - mx), e2 = __expf(l2 - mx);
    float inv = 1.0f / (e0 + e1 + e2);
    float a0 = e0 * inv, a1 = e1 * inv, a2 = e2 * inv;
    if (WRITE_OUT) {
      if (sub == 0) {
        attn_out[row] = a0;
        attn_out[NROWS + row] = a1;
        attn_out[2 * NROWS + row] = a2;
      }
    }
    float w0 = a0 + EPSW, w1 = a1 + EPSW, w2 = a2 + EPSW;
    aW0 += w0; aW1 += w1; aW2 += w2;
    float c0 = w0 * rs, c1 = w1 * rs, c2 = w2 * rs;
    aC0 = fmaf(c0, mean, aC0);
    aC1 = fmaf(c1, mean, aC1);
    aC2 = fmaf(c2, mean, aC2);
    m0x = fmaf(c0, v.x, m0x); m0y = fmaf(c0, v.y, m0y);
    m0z = fmaf(c0, v.z, m0z); m0w = fmaf(c0, v.w, m0w);
    m1x = fmaf(c1, v.x, m1x); m1y = fmaf(c1, v.y, m1y);
    m1z = fmaf(c1, v.z, m1z); m1w = fmaf(c1, v.w, m1w);
    m2x = fmaf(c2, v.x, m2x); m2y = fmaf(c2, v.y, m2y);
    m2z = fmaf(c2, v.z, m2z); m2w = fmaf(c2, v.w, m2w);
  };

  const float4* xb = (const float4*)x;
  const int gw = blockIdx.x * 4 + wid;          // 0..8191 global wave id
  // wave region: 1024 consecutive float4 = 64 rows; 8 iters x 2 loads x 64 f4
#pragma unroll 1
  for (int t = 0; t < 8; ++t) {
    const size_t base = (size_t)gw * 1024 + (size_t)t * 128;
    float4 v0 = xb[base + lane];
    float4 v1 = xb[base + 64 + lane];
    const int r0 = (int)(base >> 4) + grp;      // rows r0..r0+3 across groups
    proc(v0, r0);
    proc(v1, r0 + 4);
  }

  // fold accM over the 4 row-groups (masks 16/32 cross groups)
#pragma unroll
  for (int m = 16; m < 64; m <<= 1) {
    m0x += __shfl_xor(m0x, m, 64); m0y += __shfl_xor(m0y, m, 64);
    m0z += __shfl_xor(m0z, m, 64); m0w += __shfl_xor(m0w, m, 64);
    m1x += __shfl_xor(m1x, m, 64); m1y += __shfl_xor(m1y, m, 64);
    m1z += __shfl_xor(m1z, m, 64); m1w += __shfl_xor(m1w, m, 64);
    m2x += __shfl_xor(m2x, m, 64); m2y += __shfl_xor(m2y, m, 64);
    m2z += __shfl_xor(m2z, m, 64); m2w += __shfl_xor(m2w, m, 64);
  }
  __shared__ float redM[4][192];
  __shared__ float redS[4][6];
  if (grp == 0) {
    *reinterpret_cast<float4*>(&redM[wid][0 * 64 + 4 * sub]) = make_float4(m0x, m0y, m0z, m0w);
    *reinterpret_cast<float4*>(&redM[wid][1 * 64 + 4 * sub]) = make_float4(m1x, m1y, m1z, m1w);
    *reinterpret_cast<float4*>(&redM[wid][2 * 64 + 4 * sub]) = make_float4(m2x, m2y, m2z, m2w);
  }
  aW0 = wave_sum(aW0); aW1 = wave_sum(aW1); aW2 = wave_sum(aW2);
  aC0 = wave_sum(aC0); aC1 = wave_sum(aC1); aC2 = wave_sum(aC2);
  if (lane == 0) {
    redS[wid][0] = aW0; redS[wid][1] = aW1; redS[wid][2] = aW2;
    redS[wid][3] = aC0; redS[wid][4] = aC1; redS[wid][5] = aC2;
  }
  __syncthreads();
  if (tid < 192)
    atomicAdd(&M_out[tid], redM[0][tid] + redM[1][tid] + redM[2][tid] + redM[3][tid]);
  if (tid < 6) {
    float v = (redS[0][tid] + redS[1][tid] + redS[2][tid] + redS[3][tid]) * 0.0625f;
    if (tid < 3) atomicAdd(&W_out[tid], v);
    else         atomicAdd(&CM_out[tid - 3], v);
  }
  __threadfence();
  __shared__ int lastFlag;
  __syncthreads();
  if (tid == 0) lastFlag = (atomicAdd(done, 1) == NBLK - 1) ? 1 : 0;
  __syncthreads();
  if (!lastFlag) return;
  finalize(tid, ws, set, out_slots, fp);
}

// ---------------- launcher ----------------
extern "C" void kernel_launch(void* const* d_in, const int* in_sizes, int n_in,
                              void* d_out, int out_size, void* d_ws, size_t ws_size,
                              hipStream_t stream)
{
  (void)in_sizes; (void)n_in; (void)out_size; (void)ws_size;
  const float* x         = (const float*)d_in[0];
  const float* noise_fg  = (const float*)d_in[1];
  const float* noise_bg  = (const float*)d_in[2];
  const float* ln_in_g   = (const float*)d_in[3];
  const float* ln_in_b   = (const float*)d_in[4];
  const float* mu_fg     = (const float*)d_in[5];
  const float* logsig_fg = (const float*)d_in[6];
  const float* mu_bg     = (const float*)d_in[7];
  const float* logsig_bg = (const float*)d_in[8];
  const float* Wk        = (const float*)d_in[9];
  const float* Wv        = (const float*)d_in[10];
  const float* lnq_fg_g  = (const float*)d_in[11];
  const float* lnq_fg_b  = (const float*)d_in[12];
  const float* Wq_fg     = (const float*)d_in[13];
  const float* lnq_bg_g  = (const float*)d_in[14];
  const float* lnq_bg_b  = (const float*)d_in[15];
  const float* Wq_bg     = (const float*)d_in[16];
  const float* gfg_wih   = (const float*)d_in[17];
  const float* gfg_whh   = (const float*)d_in[18];
  const float* gfg_bih   = (const float*)d_in[19];
  const float* gfg_bhh   = (const float*)d_in[20];
  const float* gbg_wih   = (const float*)d_in[21];
  const float* gbg_whh   = (const float*)d_in[22];
  const float* gbg_bih   = (const float*)d_in[23];
  const float* gbg_bhh   = (const float*)d_in[24];
  const float* mfg_ln_g  = (const float*)d_in[25];
  const float* mfg_ln_b  = (const float*)d_in[26];
  const float* mfg_w1    = (const float*)d_in[27];
  const float* mfg_b1    = (const float*)d_in[28];
  const float* mfg_w2    = (const float*)d_in[29];
  const float* mfg_b2    = (const float*)d_in[30];
  const float* mbg_ln_g  = (const float*)d_in[31];
  const float* mbg_ln_b  = (const float*)d_in[32];
  const float* mbg_w1    = (const float*)d_in[33];
  const float* mbg_b1    = (const float*)d_in[34];
  const float* mbg_w2    = (const float*)d_in[35];
  const float* mbg_b2    = (const float*)d_in[36];

  float* ws  = (float*)d_ws;
  float* out = (float*)d_out;

  TArgs ta;
  ta.j[0]  = {Wv,      64 * 64,  6, OFF_WVT};
  ta.j[1]  = {gbg_wih, 192 * 64, 6, OFF_WIHT_BG};
  ta.j[2]  = {gbg_whh, 192 * 64, 6, OFF_WHHT_BG};
  ta.j[3]  = {gfg_wih, 192 * 64, 6, OFF_WIHT_FG};
  ta.j[4]  = {gfg_whh, 192 * 64, 6, OFF_WHHT_FG};
  ta.j[5]  = {mbg_w1,  128 * 64, 6, OFF_W1T_BG};
  ta.j[6]  = {mbg_w2,  64 * 128, 7, OFF_W2T_BG};
  ta.j[7]  = {mfg_w1,  128 * 64, 6, OFF_W1T_FG};
  ta.j[8]  = {mfg_w2,  64 * 128, 7, OFF_W2T_FG};
  ta.j[9]  = {Wq_bg,   64 * 64,  6, OFF_WQT_BG};
  ta.j[10] = {Wq_fg,   64 * 64,  6, OFF_WQT_FG};

  prep_k<<<13, 256, 0, stream>>>(ta, noise_fg, noise_bg, ln_in_g, ln_in_b,
                                 mu_fg, logsig_fg, mu_bg, logsig_bg,
                                 lnq_fg_g, lnq_fg_b, lnq_bg_g, lnq_bg_b,
                                 Wk, Wq_bg, Wq_fg, ws);

  FinPtrs fp = {ln_in_g, ln_in_b, gbg_bih, gbg_bhh, gfg_bih, gfg_bhh,
                mbg_ln_g, mbg_ln_b, mfg_ln_g, mfg_ln_b, mbg_b1, mbg_b2, mfg_b1, mfg_b2,
                lnq_fg_g, lnq_fg_b, lnq_bg_g, lnq_bg_b, Wk};

  attn_pass_k<0><<<2048, 256, 0, stream>>>(x, ws, 0, nullptr, nullptr, fp);
  attn_pass_k<1><<<2048, 256, 0, stream>>>(x, ws, 1, out + 192, out, fp);
}

// Round 7
// 487.275 us; speedup vs baseline: 1.8087x; 1.8087x over previous
//
#include <hip/hip_runtime.h>
#include <math.h>

#define NROWS 524288
constexpr float EPSW = 1e-8f;
constexpr int TILE_ROWS = 32;            // 8 KB per tile
constexpr int NTILES = NROWS / TILE_ROWS;

// ---------------- workspace layout (float offsets) ----------------
constexpr int OFF_WVT     = 0;       // 64x64   WvT[d][j]
constexpr int OFF_WIHT_BG = 4096;    // 64x192
constexpr int OFF_WHHT_BG = 16384;
constexpr int OFF_WIHT_FG = 28672;
constexpr int OFF_WHHT_FG = 40960;
constexpr int OFF_W1T_BG  = 53248;   // 64x128
constexpr int OFF_W2T_BG  = 61440;   // 128x64
constexpr int OFF_W1T_FG  = 69632;
constexpr int OFF_W2T_FG  = 77824;
constexpr int OFF_WQT_BG  = 86016;   // 64x64
constexpr int OFF_WQT_FG  = 90112;
constexpr int OFF_SLOTS   = 94208;   // 3x64
constexpr int OFF_QG      = 94400;   // 2 sets x 3 x 64
constexpr int OFF_QS      = 94784;   // 2 sets x 6
constexpr int OFF_M       = 94800;   // 2 sets x 192
constexpr int OFF_W       = 95184;   // 2 sets x 3 (then CM 2x3)
constexpr int OFF_CM      = 95190;
constexpr int OFF_DONE    = 95200;   // 2 ints

__device__ __forceinline__ float wave_sum(float v) {
#pragma unroll
  for (int m = 1; m < 64; m <<= 1) v += __shfl_xor(v, m, 64);
  return v;
}

// sum across the 16-lane subgroup via pure DPP (VALU pipe, no LDS)
__device__ __forceinline__ float dpp_sum16(float v) {
  float t;
  t = __int_as_float(__builtin_amdgcn_update_dpp(0, __float_as_int(v), 0xB1, 0xF, 0xF, true)); v += t;  // xor1
  t = __int_as_float(__builtin_amdgcn_update_dpp(0, __float_as_int(v), 0x4E, 0xF, 0xF, true)); v += t;  // xor2
  t = __int_as_float(__builtin_amdgcn_update_dpp(0, __float_as_int(v), 0x124, 0xF, 0xF, true)); v += t; // row_ror:4
  t = __int_as_float(__builtin_amdgcn_update_dpp(0, __float_as_int(v), 0x128, 0xF, 0xF, true)); v += t; // row_ror:8
  return v;
}

// ---------------- q -> qk -> (qg, QG, QB) for one slot (one wave) ----------------
__device__ void emit_q(int lane, float snew,
                       const float* __restrict__ lnq_g, const float* __restrict__ lnq_b,
                       const float* WqT, int qstride, const float* __restrict__ Wk,
                       const float* __restrict__ g_in, const float* __restrict__ b_in,
                       float* scratch,
                       float* __restrict__ qg_out, float* __restrict__ qs_out, int s)
{
  float mean = wave_sum(snew) * (1.0f / 64.0f);
  float d = snew - mean;
  float var = wave_sum(d * d) * (1.0f / 64.0f);
  float lns = d * rsqrtf(var + 1e-5f) * lnq_g[lane] + lnq_b[lane];
  scratch[lane] = lns;
  float q = 0.f;
#pragma unroll 8
  for (int dd = 0; dd < 64; ++dd) q = fmaf(scratch[dd], WqT[dd * qstride + lane], q);
  q *= 0.125f;
  scratch[lane] = q;
  float qk = 0.f;
#pragma unroll 8
  for (int j = 0; j < 64; ++j) qk = fmaf(scratch[j], Wk[j * 64 + lane], qk);
  float qgv = qk * g_in[lane];
  qg_out[lane] = qgv;
  float QG = wave_sum(qgv);
  float QB = wave_sum(qk * b_in[lane]);
  if (lane == 0) { qs_out[s] = QG; qs_out[3 + s] = QB; }
}

// ---------------- prep: transposes + zero + init (13 blocks) ----------------
struct TJob { const float* src; int RC; int Cshift; int dstOff; };
struct TArgs { TJob j[11]; };

__global__ void prep_k(TArgs a,
                       const float* __restrict__ noise_fg, const float* __restrict__ noise_bg,
                       const float* __restrict__ g_in, const float* __restrict__ b_in,
                       const float* __restrict__ mu_fg, const float* __restrict__ logsig_fg,
                       const float* __restrict__ mu_bg, const float* __restrict__ logsig_bg,
                       const float* __restrict__ lnq_fg_g, const float* __restrict__ lnq_fg_b,
                       const float* __restrict__ lnq_bg_g, const float* __restrict__ lnq_bg_b,
                       const float* __restrict__ Wk,
                       const float* __restrict__ Wq_bg, const float* __restrict__ Wq_fg,
                       float* __restrict__ ws)
{
  __shared__ float wqT[2][64 * 65];
  __shared__ float scratch[64];
  const int b = blockIdx.x, tid = threadIdx.x;
  if (b < 11) {
    TJob jb = a.j[b];
    const int C = 1 << jb.Cshift;
    const int R = jb.RC >> jb.Cshift;
    float* dst = ws + jb.dstOff;
    for (int e = tid; e < jb.RC; e += blockDim.x) {
      int r = e >> jb.Cshift;
      int c = e & (C - 1);
      dst[c * R + r] = jb.src[e];
    }
  } else if (b == 11) {
    for (int i = tid; i < 384; i += 256) ws[OFF_M + i] = 0.f;
    if (tid < 12) ws[OFF_W + tid] = 0.f;
    if (tid < 2) ((int*)(ws + OFF_DONE))[tid] = 0;
  } else {
    // in-block padded transpose of Wq_bg/Wq_fg, then init slots + emit_q x3
    for (int e = tid; e < 4096; e += 256) {
      int r = e >> 6, c = e & 63;
      wqT[0][c * 65 + r] = Wq_bg[e];
      wqT[1][c * 65 + r] = Wq_fg[e];
    }
    __syncthreads();
    if (tid < 64) {
      const int lane = tid;
      float s0 = mu_bg[lane] + __expf(logsig_bg[lane]) * noise_bg[lane];
      float s1 = mu_fg[lane] + __expf(logsig_fg[lane]) * noise_fg[lane];
      float s2 = mu_fg[lane] + __expf(logsig_fg[lane]) * noise_fg[64 + lane];
      ws[OFF_SLOTS + lane] = s0;
      ws[OFF_SLOTS + 64 + lane] = s1;
      ws[OFF_SLOTS + 128 + lane] = s2;
      emit_q(lane, s0, lnq_bg_g, lnq_bg_b, wqT[0], 65, Wk, g_in, b_in, scratch,
             ws + OFF_QG + 0, ws + OFF_QS, 0);
      emit_q(lane, s1, lnq_fg_g, lnq_fg_b, wqT[1], 65, Wk, g_in, b_in, scratch,
             ws + OFF_QG + 64, ws + OFF_QS, 1);
      emit_q(lane, s2, lnq_fg_g, lnq_fg_b, wqT[1], 65, Wk, g_in, b_in, scratch,
             ws + OFF_QG + 128, ws + OFF_QS, 2);
    }
  }
}

// ---------------- pointers for the fused finalizer ----------------
struct FinPtrs {
  const float *g_in, *b_in, *gbg_bih, *gbg_bhh, *gfg_bih, *gfg_bhh,
      *mbg_ln_g, *mbg_ln_b, *mfg_ln_g, *mfg_ln_b, *mbg_b1, *mbg_b2, *mfg_b1, *mfg_b2,
      *lnq_fg_g, *lnq_fg_b, *lnq_bg_g, *lnq_bg_b, *Wk;
};

// slot update: upd -> GRU -> MLP -> (emit_q for next iter | write slots)
__device__ void finalize(int tid, float* __restrict__ ws, int set,
                         float* __restrict__ out_slots, const FinPtrs fp)
{
  __shared__ float sA[3][64], sU[3][64], sH[3][64], sHid[3][128];
  const int wid = tid >> 6, lane = tid & 63;
  const bool act = (wid < 3);
  const bool bg = (wid == 0);
  float* M_out = ws + OFF_M + set * 192;
  float* W_out = ws + OFF_W + set * 3;
  float* CM_out = ws + OFF_CM + set * 3;

  float Wsum = 1.f, h = 0.f;
  if (act) {
    Wsum = atomicAdd(&W_out[wid], 0.f);
    float CM = atomicAdd(&CM_out[wid], 0.f);
    float Mv = atomicAdd(&M_out[wid * 64 + lane], 0.f);
    sA[wid][lane] = fp.g_in[lane] * (Mv - CM) + fp.b_in[lane] * Wsum;
  }
  __syncthreads();
  if (act) {
    const float* WvT = ws + OFF_WVT;
    float upd = 0.f;
#pragma unroll 8
    for (int d = 0; d < 64; ++d) upd = fmaf(sA[wid][d], WvT[d * 64 + lane], upd);
    upd /= Wsum;
    h = ws[OFF_SLOTS + wid * 64 + lane];
    sU[wid][lane] = upd; sH[wid][lane] = h;
  }
  __syncthreads();
  float hp = 0.f, lnh = 0.f;
  if (act) {
    const float* wihT = ws + (bg ? OFF_WIHT_BG : OFF_WIHT_FG);
    const float* whhT = ws + (bg ? OFF_WHHT_BG : OFF_WHHT_FG);
    const float* bih = bg ? fp.gbg_bih : fp.gfg_bih;
    const float* bhh = bg ? fp.gbg_bhh : fp.gfg_bhh;
    float gi0 = bih[lane], gi1 = bih[64 + lane], gi2 = bih[128 + lane];
    float gh0 = bhh[lane], gh1 = bhh[64 + lane], gh2 = bhh[128 + lane];
#pragma unroll 8
    for (int d = 0; d < 64; ++d) {
      float u = sU[wid][d], hh = sH[wid][d];
      const float* wi = &wihT[d * 192];
      const float* wh = &whhT[d * 192];
      gi0 = fmaf(u, wi[lane], gi0);
      gi1 = fmaf(u, wi[64 + lane], gi1);
      gi2 = fmaf(u, wi[128 + lane], gi2);
      gh0 = fmaf(hh, wh[lane], gh0);
      gh1 = fmaf(hh, wh[64 + lane], gh1);
      gh2 = fmaf(hh, wh[128 + lane], gh2);
    }
    float r = 1.f / (1.f + __expf(-(gi0 + gh0)));
    float z = 1.f / (1.f + __expf(-(gi1 + gh1)));
    float nn = tanhf(fmaf(r, gh2, gi2));
    hp = (1.f - z) * nn + z * h;
    float mean = wave_sum(hp) * (1.f / 64.f);
    float dv = hp - mean;
    float var = wave_sum(dv * dv) * (1.f / 64.f);
    const float* mlg = bg ? fp.mbg_ln_g : fp.mfg_ln_g;
    const float* mlb = bg ? fp.mbg_ln_b : fp.mfg_ln_b;
    lnh = dv * rsqrtf(var + 1e-5f) * mlg[lane] + mlb[lane];
  }
  __syncthreads();
  if (act) sA[wid][lane] = lnh;
  __syncthreads();
  if (act) {
    const float* w1T = ws + (bg ? OFF_W1T_BG : OFF_W1T_FG);
    const float* b1 = bg ? fp.mbg_b1 : fp.mfg_b1;
    float h1a = b1[lane], h1b = b1[64 + lane];
#pragma unroll 8
    for (int d = 0; d < 64; ++d) {
      float t = sA[wid][d];
      h1a = fmaf(t, w1T[d * 128 + lane], h1a);
      h1b = fmaf(t, w1T[d * 128 + 64 + lane], h1b);
    }
    sHid[wid][lane] = fmaxf(h1a, 0.f);
    sHid[wid][64 + lane] = fmaxf(h1b, 0.f);
  }
  __syncthreads();
  if (act) {
    const float* w2T = ws + (bg ? OFF_W2T_BG : OFF_W2T_FG);
    const float* b2 = bg ? fp.mbg_b2 : fp.mfg_b2;
    float o = b2[lane];
#pragma unroll 8
    for (int j = 0; j < 128; ++j) o = fmaf(sHid[wid][j], w2T[j * 64 + lane], o);
    float snew = hp + o;
    ws[OFF_SLOTS + wid * 64 + lane] = snew;
    if (out_slots) {
      out_slots[wid * 64 + lane] = snew;
    } else {
      const float* lqg = bg ? fp.lnq_bg_g : fp.lnq_fg_g;
      const float* lqb = bg ? fp.lnq_bg_b : fp.lnq_fg_b;
      int so = set ^ 1;
      emit_q(lane, snew, lqg, lqb, ws + (bg ? OFF_WQT_BG : OFF_WQT_FG), 64,
             fp.Wk, fp.g_in, fp.b_in, sA[wid],
             ws + OFF_QG + so * 192 + wid * 64, ws + OFF_QS + so * 6, wid);
    }
  }
}

// ---------------- streaming attention pass: per-wave double-buffered LDS pipeline ----------------
template <int WRITE_OUT>
__launch_bounds__(192, 1) __global__ void attn_pass_k(
    const float* __restrict__ x, float* __restrict__ ws, int set,
    float* __restrict__ attn_out, float* __restrict__ out_slots, FinPtrs fp)
{
  constexpr int NBLK = 768;
  __shared__ float lbuf[3][2][TILE_ROWS * 64];   // 3 waves x dbuf x 8KB = 48 KB
  __shared__ float redM[3][192];
  __shared__ float redS[3][6];
  __shared__ int lastFlag;

  const float* qg = ws + OFF_QG + set * 192;
  const float* qs = ws + OFF_QS + set * 6;
  float* M_out = ws + OFF_M + set * 192;
  float* W_out = ws + OFF_W + set * 3;
  float* CM_out = ws + OFF_CM + set * 3;
  int* done = (int*)(ws + OFF_DONE) + set;

  const int tid = threadIdx.x, wid = tid >> 6, lane = tid & 63;
  const int sub = lane & 15, grp = lane >> 4;
  const float4* qgv = (const float4*)qg;
  const float4 qg0 = qgv[sub], qg1 = qgv[16 + sub], qg2 = qgv[32 + sub];
  const float QG0 = qs[0], QG1 = qs[1], QG2 = qs[2];
  const float QB0 = qs[3], QB1 = qs[4], QB2 = qs[5];

  float m0x = 0, m0y = 0, m0z = 0, m0w = 0;
  float m1x = 0, m1y = 0, m1z = 0, m1w = 0;
  float m2x = 0, m2y = 0, m2z = 0, m2w = 0;
  float aW0 = 0, aW1 = 0, aW2 = 0, aC0 = 0, aC1 = 0, aC2 = 0;

  // process one 32-row tile resident in LDS
  auto process = [&](const float* __restrict__ buf, int t) {
#pragma unroll
    for (int i = 0; i < 8; ++i) {
      const int r = i * 4 + grp;
      const float4 v = *(const float4*)(buf + r * 64 + 4 * sub);
      float s  = (v.x + v.y) + (v.z + v.w);
      float q2 = fmaf(v.x, v.x, fmaf(v.y, v.y, fmaf(v.z, v.z, v.w * v.w)));
      float d0 = fmaf(v.x, qg0.x, fmaf(v.y, qg0.y, fmaf(v.z, qg0.z, v.w * qg0.w)));
      float d1 = fmaf(v.x, qg1.x, fmaf(v.y, qg1.y, fmaf(v.z, qg1.z, v.w * qg1.w)));
      float d2 = fmaf(v.x, qg2.x, fmaf(v.y, qg2.y, fmaf(v.z, qg2.z, v.w * qg2.w)));
      s = dpp_sum16(s); q2 = dpp_sum16(q2);
      d0 = dpp_sum16(d0); d1 = dpp_sum16(d1); d2 = dpp_sum16(d2);
      float mean = s * 0.015625f;
      float var  = fmaf(q2, 0.015625f, -mean * mean);
      float rs   = rsqrtf(var + 1e-5f);
      float l0 = fmaf(rs, fmaf(-mean, QG0, d0), QB0);
      float l1 = fmaf(rs, fmaf(-mean, QG1, d1), QB1);
      float l2 = fmaf(rs, fmaf(-mean, QG2, d2), QB2);
      float mx = fmaxf(l0, fmaxf(l1, l2));
      float e0 = __expf(l0 - mx), e1 = __expf(l1 - mx), e2 = __expf(l2 - mx);
      float inv = 1.0f / (e0 + e1 + e2);
      float a0 = e0 * inv, a1 = e1 * inv, a2 = e2 * inv;
      if (WRITE_OUT) {
        if (sub == 0) {
          const int row = t * TILE_ROWS + r;
          attn_out[row] = a0;
          attn_out[NROWS + row] = a1;
          attn_out[2 * NROWS + row] = a2;
        }
      }
      float w0 = a0 + EPSW, w1 = a1 + EPSW, w2 = a2 + EPSW;
      aW0 += w0; aW1 += w1; aW2 += w2;
      float c0 = w0 * rs, c1 = w1 * rs, c2 = w2 * rs;
      aC0 = fmaf(c0, mean, aC0);
      aC1 = fmaf(c1, mean, aC1);
      aC2 = fmaf(c2, mean, aC2);
      m0x = fmaf(c0, v.x, m0x); m0y = fmaf(c0, v.y, m0y);
      m0z = fmaf(c0, v.z, m0z); m0w = fmaf(c0, v.w, m0w);
      m1x = fmaf(c1, v.x, m1x); m1y = fmaf(c1, v.y, m1y);
      m1z = fmaf(c1, v.z, m1z); m1w = fmaf(c1, v.w, m1w);
      m2x = fmaf(c2, v.x, m2x); m2y = fmaf(c2, v.y, m2y);
      m2z = fmaf(c2, v.z, m2z); m2w = fmaf(c2, v.w, m2w);
    }
  };

  const int nwaves = NBLK * 3;
  const int wgid = blockIdx.x * 3 + wid;
  const float4* xb = (const float4*)x;
  float* b0 = lbuf[wid][0];
  float* b1 = lbuf[wid][1];

  int t = wgid;
  if (t < NTILES) {
    // prologue: fill buffer 0 directly
    const float4* g = xb + (size_t)t * 512 + lane;
    float4 p0 = g[0], p1 = g[64], p2 = g[128], p3 = g[192],
           p4 = g[256], p5 = g[320], p6 = g[384], p7 = g[448];
    float4* d = (float4*)b0 + lane;
    d[0] = p0; d[64] = p1; d[128] = p2; d[192] = p3;
    d[256] = p4; d[320] = p5; d[384] = p6; d[448] = p7;
  }
  int cur = 0;
  while (t < NTILES) {
    const int tn = t + nwaves;
    const bool have = (tn < NTILES);
    float4 p0, p1, p2, p3, p4, p5, p6, p7;
    if (have) {  // issue next tile's loads before compute (overlap)
      const float4* g = xb + (size_t)tn * 512 + lane;
      p0 = g[0]; p1 = g[64]; p2 = g[128]; p3 = g[192];
      p4 = g[256]; p5 = g[320]; p6 = g[384]; p7 = g[448];
    }
    process(cur ? b1 : b0, t);
    if (have) {  // stage into the other buffer for next iteration
      float4* d = (float4*)(cur ? b0 : b1) + lane;
      d[0] = p0; d[64] = p1; d[128] = p2; d[192] = p3;
      d[256] = p4; d[320] = p5; d[384] = p6; d[448] = p7;
    }
    cur ^= 1;
    t = tn;
  }

  // fold accM over the 4 row-groups (masks 16/32 cross groups)
#pragma unroll
  for (int m = 16; m < 64; m <<= 1) {
    m0x += __shfl_xor(m0x, m, 64); m0y += __shfl_xor(m0y, m, 64);
    m0z += __shfl_xor(m0z, m, 64); m0w += __shfl_xor(m0w, m, 64);
    m1x += __shfl_xor(m1x, m, 64); m1y += __shfl_xor(m1y, m, 64);
    m1z += __shfl_xor(m1z, m, 64); m1w += __shfl_xor(m1w, m, 64);
    m2x += __shfl_xor(m2x, m, 64); m2y += __shfl_xor(m2y, m, 64);
    m2z += __shfl_xor(m2z, m, 64); m2w += __shfl_xor(m2w, m, 64);
  }
  if (grp == 0) {
    *reinterpret_cast<float4*>(&redM[wid][0 * 64 + 4 * sub]) = make_float4(m0x, m0y, m0z, m0w);
    *reinterpret_cast<float4*>(&redM[wid][1 * 64 + 4 * sub]) = make_float4(m1x, m1y, m1z, m1w);
    *reinterpret_cast<float4*>(&redM[wid][2 * 64 + 4 * sub]) = make_float4(m2x, m2y, m2z, m2w);
  }
  aW0 = wave_sum(aW0); aW1 = wave_sum(aW1); aW2 = wave_sum(aW2);
  aC0 = wave_sum(aC0); aC1 = wave_sum(aC1); aC2 = wave_sum(aC2);
  if (lane == 0) {
    redS[wid][0] = aW0; redS[wid][1] = aW1; redS[wid][2] = aW2;
    redS[wid][3] = aC0; redS[wid][4] = aC1; redS[wid][5] = aC2;
  }
  __syncthreads();
  atomicAdd(&M_out[tid], redM[0][tid] + redM[1][tid] + redM[2][tid]);
  if (tid < 6) {
    float v = (redS[0][tid] + redS[1][tid] + redS[2][tid]) * 0.0625f;
    if (tid < 3) atomicAdd(&W_out[tid], v);
    else         atomicAdd(&CM_out[tid - 3], v);
  }
  __threadfence();
  __syncthreads();
  if (tid == 0) lastFlag = (atomicAdd(done, 1) == NBLK - 1) ? 1 : 0;
  __syncthreads();
  if (!lastFlag) return;
  finalize(tid, ws, set, out_slots, fp);
}

// ---------------- launcher ----------------
extern "C" void kernel_launch(void* const* d_in, const int* in_sizes, int n_in,
                              void* d_out, int out_size, void* d_ws, size_t ws_size,
                              hipStream_t stream)
{
  (void)in_sizes; (void)n_in; (void)out_size; (void)ws_size;
  const float* x         = (const float*)d_in[0];
  const float* noise_fg  = (const float*)d_in[1];
  const float* noise_bg  = (const float*)d_in[2];
  const float* ln_in_g   = (const float*)d_in[3];
  const float* ln_in_b   = (const float*)d_in[4];
  const float* mu_fg     = (const float*)d_in[5];
  const float* logsig_fg = (const float*)d_in[6];
  const float* mu_bg     = (const float*)d_in[7];
  const float* logsig_bg = (const float*)d_in[8];
  const float* Wk        = (const float*)d_in[9];
  const float* Wv        = (const float*)d_in[10];
  const float* lnq_fg_g  = (const float*)d_in[11];
  const float* lnq_fg_b  = (const float*)d_in[12];
  const float* Wq_fg     = (const float*)d_in[13];
  const float* lnq_bg_g  = (const float*)d_in[14];
  const float* lnq_bg_b  = (const float*)d_in[15];
  const float* Wq_bg     = (const float*)d_in[16];
  const float* gfg_wih   = (const float*)d_in[17];
  const float* gfg_whh   = (const float*)d_in[18];
  const float* gfg_bih   = (const float*)d_in[19];
  const float* gfg_bhh   = (const float*)d_in[20];
  const float* gbg_wih   = (const float*)d_in[21];
  const float* gbg_whh   = (const float*)d_in[22];
  const float* gbg_bih   = (const float*)d_in[23];
  const float* gbg_bhh   = (const float*)d_in[24];
  const float* mfg_ln_g  = (const float*)d_in[25];
  const float* mfg_ln_b  = (const float*)d_in[26];
  const float* mfg_w1    = (const float*)d_in[27];
  const float* mfg_b1    = (const float*)d_in[28];
  const float* mfg_w2    = (const float*)d_in[29];
  const float* mfg_b2    = (const float*)d_in[30];
  const float* mbg_ln_g  = (const float*)d_in[31];
  const float* mbg_ln_b  = (const float*)d_in[32];
  const float* mbg_w1    = (const float*)d_in[33];
  const float* mbg_b1    = (const float*)d_in[34];
  const float* mbg_w2    = (const float*)d_in[35];
  const float* mbg_b2    = (const float*)d_in[36];

  float* ws  = (float*)d_ws;
  float* out = (float*)d_out;

  TArgs ta;
  ta.j[0]  = {Wv,      64 * 64,  6, OFF_WVT};
  ta.j[1]  = {gbg_wih, 192 * 64, 6, OFF_WIHT_BG};
  ta.j[2]  = {gbg_whh, 192 * 64, 6, OFF_WHHT_BG};
  ta.j[3]  = {gfg_wih, 192 * 64, 6, OFF_WIHT_FG};
  ta.j[4]  = {gfg_whh, 192 * 64, 6, OFF_WHHT_FG};
  ta.j[5]  = {mbg_w1,  128 * 64, 6, OFF_W1T_BG};
  ta.j[6]  = {mbg_w2,  64 * 128, 7, OFF_W2T_BG};
  ta.j[7]  = {mfg_w1,  128 * 64, 6, OFF_W1T_FG};
  ta.j[8]  = {mfg_w2,  64 * 128, 7, OFF_W2T_FG};
  ta.j[9]  = {Wq_bg,   64 * 64,  6, OFF_WQT_BG};
  ta.j[10] = {Wq_fg,   64 * 64,  6, OFF_WQT_FG};

  prep_k<<<13, 256, 0, stream>>>(ta, noise_fg, noise_bg, ln_in_g, ln_in_b,
                                 mu_fg, logsig_fg, mu_bg, logsig_bg,
                                 lnq_fg_g, lnq_fg_b, lnq_bg_g, lnq_bg_b,
                                 Wk, Wq_bg, Wq_fg, ws);

  FinPtrs fp = {ln_in_g, ln_in_b, gbg_bih, gbg_bhh, gfg_bih, gfg_bhh,
                mbg_ln_g, mbg_ln_b, mfg_ln_g, mfg_ln_b, mbg_b1, mbg_b2, mfg_b1, mfg_b2,
                lnq_fg_g, lnq_fg_b, lnq_bg_g, lnq_bg_b, Wk};

  attn_pass_k<0><<<768, 192, 0, stream>>>(x, ws, 0, nullptr, nullptr, fp);
  attn_pass_k<1><<<768, 192, 0, stream>>>(x, ws, 1, out + 192, out, fp);
}

// Round 8
// 473.840 us; speedup vs baseline: 1.8599x; 1.0284x over previous
//
#include <hip/hip_runtime.h>
#include <math.h>

#define NROWS 524288
constexpr float EPSW = 1e-8f;
constexpr int TILE_ROWS = 32;            // 8 KB per tile
constexpr int NTILES = NROWS / TILE_ROWS;
constexpr int NREP = 32;                 // atomic-contention replicas
constexpr int PROW = 208;                // partial row stride (192 M + 3 W + 3 CM, padded)

// ---------------- workspace layout (float offsets) ----------------
constexpr int OFF_WVT     = 0;       // 64x64   WvT[d][j]
constexpr int OFF_WIHT_BG = 4096;    // 64x192
constexpr int OFF_WHHT_BG = 16384;
constexpr int OFF_WIHT_FG = 28672;
constexpr int OFF_WHHT_FG = 40960;
constexpr int OFF_W1T_BG  = 53248;   // 64x128
constexpr int OFF_W2T_BG  = 61440;   // 128x64
constexpr int OFF_W1T_FG  = 69632;
constexpr int OFF_W2T_FG  = 77824;
constexpr int OFF_WQT_BG  = 86016;   // 64x64
constexpr int OFF_WQT_FG  = 90112;
constexpr int OFF_SLOTS   = 94208;   // 3x64
constexpr int OFF_QG      = 94400;   // 2 sets x 3 x 64
constexpr int OFF_QS      = 94784;   // 2 sets x 6
constexpr int OFF_PART    = 94800;   // 2 sets x NREP x PROW partials
constexpr int OFF_DONE    = 94800 + 2 * NREP * PROW;  // 2 ints

__device__ __forceinline__ float wave_sum(float v) {
#pragma unroll
  for (int m = 1; m < 64; m <<= 1) v += __shfl_xor(v, m, 64);
  return v;
}

// sum across the 16-lane subgroup via pure DPP (VALU pipe, no LDS)
__device__ __forceinline__ float dpp_sum16(float v) {
  float t;
  t = __int_as_float(__builtin_amdgcn_update_dpp(0, __float_as_int(v), 0xB1, 0xF, 0xF, true)); v += t;  // xor1
  t = __int_as_float(__builtin_amdgcn_update_dpp(0, __float_as_int(v), 0x4E, 0xF, 0xF, true)); v += t;  // xor2
  t = __int_as_float(__builtin_amdgcn_update_dpp(0, __float_as_int(v), 0x124, 0xF, 0xF, true)); v += t; // row_ror:4
  t = __int_as_float(__builtin_amdgcn_update_dpp(0, __float_as_int(v), 0x128, 0xF, 0xF, true)); v += t; // row_ror:8
  return v;
}

// ---------------- q -> qk -> (qg, QG, QB) for one slot (one wave) ----------------
__device__ void emit_q(int lane, float snew,
                       const float* __restrict__ lnq_g, const float* __restrict__ lnq_b,
                       const float* WqT, int qstride, const float* __restrict__ Wk,
                       const float* __restrict__ g_in, const float* __restrict__ b_in,
                       float* scratch,
                       float* __restrict__ qg_out, float* __restrict__ qs_out, int s)
{
  float mean = wave_sum(snew) * (1.0f / 64.0f);
  float d = snew - mean;
  float var = wave_sum(d * d) * (1.0f / 64.0f);
  float lns = d * rsqrtf(var + 1e-5f) * lnq_g[lane] + lnq_b[lane];
  scratch[lane] = lns;
  float q = 0.f;
#pragma unroll 8
  for (int dd = 0; dd < 64; ++dd) q = fmaf(scratch[dd], WqT[dd * qstride + lane], q);
  q *= 0.125f;
  scratch[lane] = q;
  float qk = 0.f;
#pragma unroll 8
  for (int j = 0; j < 64; ++j) qk = fmaf(scratch[j], Wk[j * 64 + lane], qk);
  float qgv = qk * g_in[lane];
  qg_out[lane] = qgv;
  float QG = wave_sum(qgv);
  float QB = wave_sum(qk * b_in[lane]);
  if (lane == 0) { qs_out[s] = QG; qs_out[3 + s] = QB; }
}

// ---------------- prep: transposes + zero + init (13 blocks) ----------------
struct TJob { const float* src; int RC; int Cshift; int dstOff; };
struct TArgs { TJob j[11]; };

__global__ void prep_k(TArgs a,
                       const float* __restrict__ noise_fg, const float* __restrict__ noise_bg,
                       const float* __restrict__ g_in, const float* __restrict__ b_in,
                       const float* __restrict__ mu_fg, const float* __restrict__ logsig_fg,
                       const float* __restrict__ mu_bg, const float* __restrict__ logsig_bg,
                       const float* __restrict__ lnq_fg_g, const float* __restrict__ lnq_fg_b,
                       const float* __restrict__ lnq_bg_g, const float* __restrict__ lnq_bg_b,
                       const float* __restrict__ Wk,
                       const float* __restrict__ Wq_bg, const float* __restrict__ Wq_fg,
                       float* __restrict__ ws)
{
  __shared__ float wqT[2][64 * 65];
  __shared__ float scratch[64];
  const int b = blockIdx.x, tid = threadIdx.x;
  if (b < 11) {
    TJob jb = a.j[b];
    const int C = 1 << jb.Cshift;
    const int R = jb.RC >> jb.Cshift;
    float* dst = ws + jb.dstOff;
    for (int e = tid; e < jb.RC; e += blockDim.x) {
      int r = e >> jb.Cshift;
      int c = e & (C - 1);
      dst[c * R + r] = jb.src[e];
    }
  } else if (b == 11) {
    for (int i = tid; i < 2 * NREP * PROW; i += 256) ws[OFF_PART + i] = 0.f;
    if (tid < 2) ((int*)(ws + OFF_DONE))[tid] = 0;
  } else {
    // in-block padded transpose of Wq_bg/Wq_fg, then init slots + emit_q x3
    for (int e = tid; e < 4096; e += 256) {
      int r = e >> 6, c = e & 63;
      wqT[0][c * 65 + r] = Wq_bg[e];
      wqT[1][c * 65 + r] = Wq_fg[e];
    }
    __syncthreads();
    if (tid < 64) {
      const int lane = tid;
      float s0 = mu_bg[lane] + __expf(logsig_bg[lane]) * noise_bg[lane];
      float s1 = mu_fg[lane] + __expf(logsig_fg[lane]) * noise_fg[lane];
      float s2 = mu_fg[lane] + __expf(logsig_fg[lane]) * noise_fg[64 + lane];
      ws[OFF_SLOTS + lane] = s0;
      ws[OFF_SLOTS + 64 + lane] = s1;
      ws[OFF_SLOTS + 128 + lane] = s2;
      emit_q(lane, s0, lnq_bg_g, lnq_bg_b, wqT[0], 65, Wk, g_in, b_in, scratch,
             ws + OFF_QG + 0, ws + OFF_QS, 0);
      emit_q(lane, s1, lnq_fg_g, lnq_fg_b, wqT[1], 65, Wk, g_in, b_in, scratch,
             ws + OFF_QG + 64, ws + OFF_QS, 1);
      emit_q(lane, s2, lnq_fg_g, lnq_fg_b, wqT[1], 65, Wk, g_in, b_in, scratch,
             ws + OFF_QG + 128, ws + OFF_QS, 2);
    }
  }
}

// ---------------- pointers for the fused finalizer ----------------
struct FinPtrs {
  const float *g_in, *b_in, *gbg_bih, *gbg_bhh, *gfg_bih, *gfg_bhh,
      *mbg_ln_g, *mbg_ln_b, *mfg_ln_g, *mfg_ln_b, *mbg_b1, *mbg_b2, *mfg_b1, *mfg_b2,
      *lnq_fg_g, *lnq_fg_b, *lnq_bg_g, *lnq_bg_b, *Wk;
};

// slot update: reduce replica partials -> upd -> GRU -> MLP -> (emit_q | write slots)
// scr: >=1024 floats of LDS scratch (carved from lbuf; block is past streaming)
__device__ void finalize(int tid, float* __restrict__ ws, int set,
                         float* __restrict__ out_slots, const FinPtrs fp, float* scr)
{
  const int wid = tid >> 6, lane = tid & 63;
  const bool bg = (wid == 0);
  __threadfence();   // acquire: invalidate local caches before reading partials
  const float* part = ws + OFF_PART + set * (NREP * PROW);
  float accM = 0.f;
#pragma unroll 8
  for (int r = 0; r < NREP; ++r) accM += part[r * PROW + tid];      // tid<192 -> M[j=tid]
  float accS = 0.f;
  if (tid < 6) {
#pragma unroll 8
    for (int r = 0; r < NREP; ++r) accS += part[r * PROW + 192 + tid];
  }
  float* sA = scr;            // 192
  float* sU = scr + 192;      // 192
  float* sH = scr + 384;      // 192
  float* sHid = scr + 576;    // 384
  float* sWC = scr + 960;     // 6
  if (tid < 6) sWC[tid] = accS;
  __syncthreads();
  const float Wsum = sWC[wid];
  const float CM = sWC[3 + wid];
  sA[wid * 64 + lane] = fp.g_in[lane] * (accM - CM) + fp.b_in[lane] * Wsum;
  __syncthreads();
  {
    const float* WvT = ws + OFF_WVT;
    float upd = 0.f;
#pragma unroll 8
    for (int d = 0; d < 64; ++d) upd = fmaf(sA[wid * 64 + d], WvT[d * 64 + lane], upd);
    upd /= Wsum;
    sU[wid * 64 + lane] = upd;
    sH[wid * 64 + lane] = ws[OFF_SLOTS + wid * 64 + lane];
  }
  __syncthreads();
  float hp, lnh;
  const float h = sH[wid * 64 + lane];
  {
    const float* wihT = ws + (bg ? OFF_WIHT_BG : OFF_WIHT_FG);
    const float* whhT = ws + (bg ? OFF_WHHT_BG : OFF_WHHT_FG);
    const float* bih = bg ? fp.gbg_bih : fp.gfg_bih;
    const float* bhh = bg ? fp.gbg_bhh : fp.gfg_bhh;
    float gi0 = bih[lane], gi1 = bih[64 + lane], gi2 = bih[128 + lane];
    float gh0 = bhh[lane], gh1 = bhh[64 + lane], gh2 = bhh[128 + lane];
#pragma unroll 8
    for (int d = 0; d < 64; ++d) {
      float u = sU[wid * 64 + d], hh = sH[wid * 64 + d];
      const float* wi = &wihT[d * 192];
      const float* wh = &whhT[d * 192];
      gi0 = fmaf(u, wi[lane], gi0);
      gi1 = fmaf(u, wi[64 + lane], gi1);
      gi2 = fmaf(u, wi[128 + lane], gi2);
      gh0 = fmaf(hh, wh[lane], gh0);
      gh1 = fmaf(hh, wh[64 + lane], gh1);
      gh2 = fmaf(hh, wh[128 + lane], gh2);
    }
    float r = 1.f / (1.f + __expf(-(gi0 + gh0)));
    float z = 1.f / (1.f + __expf(-(gi1 + gh1)));
    float nn = tanhf(fmaf(r, gh2, gi2));
    hp = (1.f - z) * nn + z * h;
    float mean = wave_sum(hp) * (1.f / 64.f);
    float dv = hp - mean;
    float var = wave_sum(dv * dv) * (1.f / 64.f);
    const float* mlg = bg ? fp.mbg_ln_g : fp.mfg_ln_g;
    const float* mlb = bg ? fp.mbg_ln_b : fp.mfg_ln_b;
    lnh = dv * rsqrtf(var + 1e-5f) * mlg[lane] + mlb[lane];
  }
  __syncthreads();
  sA[wid * 64 + lane] = lnh;
  __syncthreads();
  {
    const float* w1T = ws + (bg ? OFF_W1T_BG : OFF_W1T_FG);
    const float* b1 = bg ? fp.mbg_b1 : fp.mfg_b1;
    float h1a = b1[lane], h1b = b1[64 + lane];
#pragma unroll 8
    for (int d = 0; d < 64; ++d) {
      float t = sA[wid * 64 + d];
      h1a = fmaf(t, w1T[d * 128 + lane], h1a);
      h1b = fmaf(t, w1T[d * 128 + 64 + lane], h1b);
    }
    sHid[wid * 128 + lane] = fmaxf(h1a, 0.f);
    sHid[wid * 128 + 64 + lane] = fmaxf(h1b, 0.f);
  }
  __syncthreads();
  {
    const float* w2T = ws + (bg ? OFF_W2T_BG : OFF_W2T_FG);
    const float* b2 = bg ? fp.mbg_b2 : fp.mfg_b2;
    float o = b2[lane];
#pragma unroll 8
    for (int j = 0; j < 128; ++j) o = fmaf(sHid[wid * 128 + j], w2T[j * 64 + lane], o);
    float snew = hp + o;
    ws[OFF_SLOTS + wid * 64 + lane] = snew;
    if (out_slots) {
      out_slots[wid * 64 + lane] = snew;
    } else {
      const float* lqg = bg ? fp.lnq_bg_g : fp.lnq_fg_g;
      const float* lqb = bg ? fp.lnq_bg_b : fp.lnq_fg_b;
      int so = set ^ 1;
      emit_q(lane, snew, lqg, lqb, ws + (bg ? OFF_WQT_BG : OFF_WQT_FG), 64,
             fp.Wk, fp.g_in, fp.b_in, sA + wid * 64,
             ws + OFF_QG + so * 192 + wid * 64, ws + OFF_QS + so * 6, wid);
    }
  }
}

// ---------------- streaming attention pass: per-wave double-buffered LDS pipeline ----------------
template <int WRITE_OUT>
__launch_bounds__(192, 1) __global__ void attn_pass_k(
    const float* __restrict__ x, float* __restrict__ ws, int set,
    float* __restrict__ attn_out, float* __restrict__ out_slots, FinPtrs fp)
{
  constexpr int NBLK = 768;
  __shared__ float lbuf[3][2][TILE_ROWS * 64];   // 3 waves x dbuf x 8KB = 48 KB
  __shared__ float redM[3][192];
  __shared__ float redS[3][6];
  __shared__ int lastFlag;

  const float* qg = ws + OFF_QG + set * 192;
  const float* qs = ws + OFF_QS + set * 6;
  int* done = (int*)(ws + OFF_DONE) + set;

  const int tid = threadIdx.x, wid = tid >> 6, lane = tid & 63;
  const int sub = lane & 15, grp = lane >> 4;
  const float4* qgv = (const float4*)qg;
  const float4 qg0 = qgv[sub], qg1 = qgv[16 + sub], qg2 = qgv[32 + sub];
  const float QG0 = qs[0], QG1 = qs[1], QG2 = qs[2];
  const float QB0 = qs[3], QB1 = qs[4], QB2 = qs[5];

  float m0x = 0, m0y = 0, m0z = 0, m0w = 0;
  float m1x = 0, m1y = 0, m1z = 0, m1w = 0;
  float m2x = 0, m2y = 0, m2z = 0, m2w = 0;
  float aW0 = 0, aW1 = 0, aW2 = 0, aC0 = 0, aC1 = 0, aC2 = 0;

  // process one 32-row tile resident in LDS
  auto process = [&](const float* __restrict__ buf, int t) {
#pragma unroll
    for (int i = 0; i < 8; ++i) {
      const int r = i * 4 + grp;
      const float4 v = *(const float4*)(buf + r * 64 + 4 * sub);
      float s  = (v.x + v.y) + (v.z + v.w);
      float q2 = fmaf(v.x, v.x, fmaf(v.y, v.y, fmaf(v.z, v.z, v.w * v.w)));
      float d0 = fmaf(v.x, qg0.x, fmaf(v.y, qg0.y, fmaf(v.z, qg0.z, v.w * qg0.w)));
      float d1 = fmaf(v.x, qg1.x, fmaf(v.y, qg1.y, fmaf(v.z, qg1.z, v.w * qg1.w)));
      float d2 = fmaf(v.x, qg2.x, fmaf(v.y, qg2.y, fmaf(v.z, qg2.z, v.w * qg2.w)));
      s = dpp_sum16(s); q2 = dpp_sum16(q2);
      d0 = dpp_sum16(d0); d1 = dpp_sum16(d1); d2 = dpp_sum16(d2);
      float mean = s * 0.015625f;
      float var  = fmaf(q2, 0.015625f, -mean * mean);
      float rs   = rsqrtf(var + 1e-5f);
      float l0 = fmaf(rs, fmaf(-mean, QG0, d0), QB0);
      float l1 = fmaf(rs, fmaf(-mean, QG1, d1), QB1);
      float l2 = fmaf(rs, fmaf(-mean, QG2, d2), QB2);
      float mx = fmaxf(l0, fmaxf(l1, l2));
      float e0 = __expf(l0 - mx), e1 = __expf(l1 - mx), e2 = __expf(l2 - mx);
      float inv = 1.0f / (e0 + e1 + e2);
      float a0 = e0 * inv, a1 = e1 * inv, a2 = e2 * inv;
      if (WRITE_OUT) {
        if (sub == 0) {
          const int row = t * TILE_ROWS + r;
          attn_out[row] = a0;
          attn_out[NROWS + row] = a1;
          attn_out[2 * NROWS + row] = a2;
        }
      }
      float w0 = a0 + EPSW, w1 = a1 + EPSW, w2 = a2 + EPSW;
      aW0 += w0; aW1 += w1; aW2 += w2;
      float c0 = w0 * rs, c1 = w1 * rs, c2 = w2 * rs;
      aC0 = fmaf(c0, mean, aC0);
      aC1 = fmaf(c1, mean, aC1);
      aC2 = fmaf(c2, mean, aC2);
      m0x = fmaf(c0, v.x, m0x); m0y = fmaf(c0, v.y, m0y);
      m0z = fmaf(c0, v.z, m0z); m0w = fmaf(c0, v.w, m0w);
      m1x = fmaf(c1, v.x, m1x); m1y = fmaf(c1, v.y, m1y);
      m1z = fmaf(c1, v.z, m1z); m1w = fmaf(c1, v.w, m1w);
      m2x = fmaf(c2, v.x, m2x); m2y = fmaf(c2, v.y, m2y);
      m2z = fmaf(c2, v.z, m2z); m2w = fmaf(c2, v.w, m2w);
    }
  };

  const int nwaves = NBLK * 3;
  const int wgid = blockIdx.x * 3 + wid;
  const float4* xb = (const float4*)x;
  float* b0 = lbuf[wid][0];
  float* b1 = lbuf[wid][1];

  int t = wgid;
  if (t < NTILES) {
    // prologue: fill buffer 0 directly
    const float4* g = xb + (size_t)t * 512 + lane;
    float4 p0 = g[0], p1 = g[64], p2 = g[128], p3 = g[192],
           p4 = g[256], p5 = g[320], p6 = g[384], p7 = g[448];
    float4* d = (float4*)b0 + lane;
    d[0] = p0; d[64] = p1; d[128] = p2; d[192] = p3;
    d[256] = p4; d[320] = p5; d[384] = p6; d[448] = p7;
  }
  int cur = 0;
  while (t < NTILES) {
    const int tn = t + nwaves;
    const bool have = (tn < NTILES);
    float4 p0, p1, p2, p3, p4, p5, p6, p7;
    if (have) {  // issue next tile's loads before compute (overlap)
      const float4* g = xb + (size_t)tn * 512 + lane;
      p0 = g[0]; p1 = g[64]; p2 = g[128]; p3 = g[192];
      p4 = g[256]; p5 = g[320]; p6 = g[384]; p7 = g[448];
    }
    process(cur ? b1 : b0, t);
    if (have) {  // stage into the other buffer for next iteration
      float4* d = (float4*)(cur ? b0 : b1) + lane;
      d[0] = p0; d[64] = p1; d[128] = p2; d[192] = p3;
      d[256] = p4; d[320] = p5; d[384] = p6; d[448] = p7;
    }
    cur ^= 1;
    t = tn;
  }

  // fold accM over the 4 row-groups (masks 16/32 cross groups)
#pragma unroll
  for (int m = 16; m < 64; m <<= 1) {
    m0x += __shfl_xor(m0x, m, 64); m0y += __shfl_xor(m0y, m, 64);
    m0z += __shfl_xor(m0z, m, 64); m0w += __shfl_xor(m0w, m, 64);
    m1x += __shfl_xor(m1x, m, 64); m1y += __shfl_xor(m1y, m, 64);
    m1z += __shfl_xor(m1z, m, 64); m1w += __shfl_xor(m1w, m, 64);
    m2x += __shfl_xor(m2x, m, 64); m2y += __shfl_xor(m2y, m, 64);
    m2z += __shfl_xor(m2z, m, 64); m2w += __shfl_xor(m2w, m, 64);
  }
  if (grp == 0) {
    *reinterpret_cast<float4*>(&redM[wid][0 * 64 + 4 * sub]) = make_float4(m0x, m0y, m0z, m0w);
    *reinterpret_cast<float4*>(&redM[wid][1 * 64 + 4 * sub]) = make_float4(m1x, m1y, m1z, m1w);
    *reinterpret_cast<float4*>(&redM[wid][2 * 64 + 4 * sub]) = make_float4(m2x, m2y, m2z, m2w);
  }
  aW0 = wave_sum(aW0); aW1 = wave_sum(aW1); aW2 = wave_sum(aW2);
  aC0 = wave_sum(aC0); aC1 = wave_sum(aC1); aC2 = wave_sum(aC2);
  if (lane == 0) {
    redS[wid][0] = aW0; redS[wid][1] = aW1; redS[wid][2] = aW2;
    redS[wid][3] = aC0; redS[wid][4] = aC1; redS[wid][5] = aC2;
  }
  __syncthreads();
  // replica-spread atomics: contention per address = NBLK/NREP = 24
  float* part = ws + OFF_PART + set * (NREP * PROW) + (blockIdx.x & (NREP - 1)) * PROW;
  atomicAdd(&part[tid], redM[0][tid] + redM[1][tid] + redM[2][tid]);
  if (tid < 6)
    atomicAdd(&part[192 + tid], (redS[0][tid] + redS[1][tid] + redS[2][tid]) * 0.0625f);
  __threadfence();
  __syncthreads();
  if (tid == 0) lastFlag = (atomicAdd(done, 1) == NBLK - 1) ? 1 : 0;
  __syncthreads();
  if (!lastFlag) return;
  finalize(tid, ws, set, out_slots, fp, &lbuf[0][0][0]);
}

// ---------------- launcher ----------------
extern "C" void kernel_launch(void* const* d_in, const int* in_sizes, int n_in,
                              void* d_out, int out_size, void* d_ws, size_t ws_size,
                              hipStream_t stream)
{
  (void)in_sizes; (void)n_in; (void)out_size; (void)ws_size;
  const float* x         = (const float*)d_in[0];
  const float* noise_fg  = (const float*)d_in[1];
  const float* noise_bg  = (const float*)d_in[2];
  const float* ln_in_g   = (const float*)d_in[3];
  const float* ln_in_b   = (const float*)d_in[4];
  const float* mu_fg     = (const float*)d_in[5];
  const float* logsig_fg = (const float*)d_in[6];
  const float* mu_bg     = (const float*)d_in[7];
  const float* logsig_bg = (const float*)d_in[8];
  const float* Wk        = (const float*)d_in[9];
  const float* Wv        = (const float*)d_in[10];
  const float* lnq_fg_g  = (const float*)d_in[11];
  const float* lnq_fg_b  = (const float*)d_in[12];
  const float* Wq_fg     = (const float*)d_in[13];
  const float* lnq_bg_g  = (const float*)d_in[14];
  const float* lnq_bg_b  = (const float*)d_in[15];
  const float* Wq_bg     = (const float*)d_in[16];
  const float* gfg_wih   = (const float*)d_in[17];
  const float* gfg_whh   = (const float*)d_in[18];
  const float* gfg_bih   = (const float*)d_in[19];
  const float* gfg_bhh   = (const float*)d_in[20];
  const float* gbg_wih   = (const float*)d_in[21];
  const float* gbg_whh   = (const float*)d_in[22];
  const float* gbg_bih   = (const float*)d_in[23];
  const float* gbg_bhh   = (const float*)d_in[24];
  const float* mfg_ln_g  = (const float*)d_in[25];
  const float* mfg_ln_b  = (const float*)d_in[26];
  const float* mfg_w1    = (const float*)d_in[27];
  const float* mfg_b1    = (const float*)d_in[28];
  const float* mfg_w2    = (const float*)d_in[29];
  const float* mfg_b2    = (const float*)d_in[30];
  const float* mbg_ln_g  = (const float*)d_in[31];
  const float* mbg_ln_b  = (const float*)d_in[32];
  const float* mbg_w1    = (const float*)d_in[33];
  const float* mbg_b1    = (const float*)d_in[34];
  const float* mbg_w2    = (const float*)d_in[35];
  const float* mbg_b2    = (const float*)d_in[36];

  float* ws  = (float*)d_ws;
  float* out = (float*)d_out;

  TArgs ta;
  ta.j[0]  = {Wv,      64 * 64,  6, OFF_WVT};
  ta.j[1]  = {gbg_wih, 192 * 64, 6, OFF_WIHT_BG};
  ta.j[2]  = {gbg_whh, 192 * 64, 6, OFF_WHHT_BG};
  ta.j[3]  = {gfg_wih, 192 * 64, 6, OFF_WIHT_FG};
  ta.j[4]  = {gfg_whh, 192 * 64, 6, OFF_WHHT_FG};
  ta.j[5]  = {mbg_w1,  128 * 64, 6, OFF_W1T_BG};
  ta.j[6]  = {mbg_w2,  64 * 128, 7, OFF_W2T_BG};
  ta.j[7]  = {mfg_w1,  128 * 64, 6, OFF_W1T_FG};
  ta.j[8]  = {mfg_w2,  64 * 128, 7, OFF_W2T_FG};
  ta.j[9]  = {Wq_bg,   64 * 64,  6, OFF_WQT_BG};
  ta.j[10] = {Wq_fg,   64 * 64,  6, OFF_WQT_FG};

  prep_k<<<13, 256, 0, stream>>>(ta, noise_fg, noise_bg, ln_in_g, ln_in_b,
                                 mu_fg, logsig_fg, mu_bg, logsig_bg,
                                 lnq_fg_g, lnq_fg_b, lnq_bg_g, lnq_bg_b,
                                 Wk, Wq_bg, Wq_fg, ws);

  FinPtrs fp = {ln_in_g, ln_in_b, gbg_bih, gbg_bhh, gfg_bih, gfg_bhh,
                mbg_ln_g, mbg_ln_b, mfg_ln_g, mfg_ln_b, mbg_b1, mbg_b2, mfg_b1, mfg_b2,
                lnq_fg_g, lnq_fg_b, lnq_bg_g, lnq_bg_b, Wk};

  attn_pass_k<0><<<768, 192, 0, stream>>>(x, ws, 0, nullptr, nullptr, fp);
  attn_pass_k<1><<<768, 192, 0, stream>>>(x, ws, 1, out + 192, out, fp);
}